// Round 9
// baseline (86.773 us; speedup 1.0000x reference)
//
#include <hip/hip_runtime.h>

// DeformableConv2D round 13: r12 numerics, 512-thread / 8-wave blocks (PW=28).
//
// r12 post-mortem: f16-only window won (bench 94.6->86.7, main ~31us, absmax
// unchanged). Residual: Occupancy ~20.7% = ~6.6 waves/CU average -- <2 resident
// blocks/CU over the kernel lifetime (896 short 4-wave blocks; ramp+tail) vs
// capacity 16 waves. The per-block serial chain (stage->A->A'->B with ~120cy
// LDS latency per phase-B tap) needs more co-resident waves to hide.
//
// This round: merge 2 adjacent blocks -> 512 thr / 8 waves, PW=28, grid 448.
//   * steady residency 2 blocks x 8 waves = 16 waves/CU (~2.4x the measured avg)
//   * staging halo amortized: 160 pos vs 2x90 (-11% staging traffic)
//   * block-fixed costs (barrier drains, A' ramp) halve
//   * wave wid: g = wid&3 (N-tile / deformable group), mt = wid>>2 (pixel half:
//     mt*14 + 0..13). Phase math identical to r12, just Mtile-split.
// LDS: s_winh 20480 + s_off 8064 + s_cww 18432 + s_cwl 9216 = 56192 B
//   -> 2 blocks/CU (LDS and wave limits agree). launch_bounds(512,4).
// Barriers per block: 3.
//
// MFMA 16x16x32 f16 layouts (verified by earlier passing runs):
//   A-frag: lane holds A[m=lane&15][k=(lane>>4)*8+j]
//   B-frag: lane holds B[k=(lane>>4)*8+j][n=lane&15]   (B stored [n][k])
//   C/D  : col(n)=lane&15, row(m)=(lane>>4)*4+reg

#define NH 56
#define NW 56
#define NC 64
#define NDG 4
#define NK 9
#define NOFF 72
#define NOFFP 80
#define NF 64
#define KTOT 576
#define HWPIX 3136
#define NPIX 12544

#define PW    28            // pixels per block (half a row; 2 segs/row)
#define PWH   14            // pixels per Mtile (wave pixel-half)
#define WR    5             // window rows  (oh-2 .. oh+2)
#define WC    32            // window cols  (ow0-2 .. ow0+29)
#define WPOS  (WR * WC)     // 160 positions
#define NBLK  (4 * NH * 2)  // 448

#define WS_OFFKT 0          // f16 [80][576]   = 92160 B
#define WS_WK    92160      // f16 [9][64][64] = 73728 B

typedef _Float16 half8   __attribute__((ext_vector_type(8)));
typedef _Float16 half4   __attribute__((ext_vector_type(4)));
typedef float    floatx4 __attribute__((ext_vector_type(4)));

// ---------------- prep: weight conversion ----------------
__global__ __launch_bounds__(256)
void dcn_prep(const float* __restrict__ offk,   // [3,3,64,72] (kk,oc)
              const float* __restrict__ wk,     // [3,3,64,64] (k,f,c)
              _Float16* __restrict__ offkt,     // [80][576]   (oc,kk)
              _Float16* __restrict__ wkh)       // [9][64][64]
{
    const int i = blockIdx.x * 256 + threadIdx.x;
    if (i < NOFFP * KTOT) {
        const int oc = i / KTOT;
        const int kk = i - oc * KTOT;
        const float v = (oc < NOFF) ? offk[kk * NOFF + oc] : 0.0f;
        offkt[i] = (_Float16)v;
    }
    const int j = i - NOFFP * KTOT;
    if (j >= 0 && j < NK * NF * NC) wkh[j] = (_Float16)wk[j];
}

// f16 window swizzle (16B granules contiguous; spread banks across pos)
__device__ __forceinline__ int winh_idx(int pos, int c) {     // elem units
    return (pos << 6) + (c ^ ((pos & 7) << 3));
}

// ---------------- fused main ----------------
__global__ __launch_bounds__(512, 4)
void dcn_main(const float* __restrict__ x,        // [4,56,56,64]
              const _Float16* __restrict__ offkt, // [80][576]
              const float* __restrict__ offb,     // [72]
              const _Float16* __restrict__ wkh,   // [9][64][64]
              float* __restrict__ out)            // [12544][64]
{
    __shared__ __align__(16) _Float16 s_winh[WPOS * NC];    // 20480 B
    __shared__ float s_off[PW * NOFF];                      // 8064 B
    __shared__ __align__(16) float s_cww[36 * 32 * 4];      // 18432 B [k*4+g][p]
    __shared__ __align__(8)  unsigned s_cwl[36 * 32 * 2];   // 9216 B  [k*4+g][p]

    const int tid  = threadIdx.x;
    const int wid  = tid >> 6;      // 0..7
    const int g    = wid & 3;       // N-tile / deformable group
    const int mt   = wid >> 2;      // pixel half: handles px mt*14 .. mt*14+13
    const int lane = tid & 63;
    const int m    = lane & 15;     // MFMA row / col index
    const int kq   = lane >> 4;     // MFMA k-quad
    const int kq8  = kq * 8;

    // block -> (b, oh, ow0)
    const int blk = blockIdx.x;
    const int b   = blk / (NH * 2);
    const int r2  = blk - b * (NH * 2);
    const int oh  = r2 >> 1;
    const int ow0 = (r2 & 1) * PW;
    const int bb  = b * HWPIX;

    // ---- stage window (f16), zero-padded outside image ----
    for (int i = tid; i < WPOS * 16; i += 512) {
        const int pos = i >> 4;
        const int g4  = (i & 15) * 4;
        const int ry  = pos / WC;
        const int rx  = pos - ry * WC;
        const int iy  = oh + ry - 2;
        const int ix  = ow0 + rx - 2;
        float4 v = make_float4(0.f, 0.f, 0.f, 0.f);
        if ((unsigned)iy < NH && (unsigned)ix < NW)
            v = *(const float4*)&x[(size_t)((bb + iy * NW + ix) * NC) + g4];
        half4 h;
        h[0] = (_Float16)v.x; h[1] = (_Float16)v.y;
        h[2] = (_Float16)v.z; h[3] = (_Float16)v.w;
        *(half4*)&s_winh[winh_idx(pos, g4)] = h;
    }
    __syncthreads();

    // ---- phase A: offset conv GEMM from f16 window ----
    const int oc0 = g * 16 + m;     // 0..63
    floatx4 acc0, acc1;
    { const float bv = offb[oc0]; acc0 = (floatx4){bv, bv, bv, bv}; }
    { const float bv = (g == 3 && m < 8) ? offb[64 + m] : 0.0f;
      acc1 = (floatx4){bv, bv, bv, bv}; }

    #pragma unroll
    for (int k = 0; k < NK; ++k) {
        const int ki = k / 3, kj = k - 3 * ki;
        // rows m>=PWH give garbage (or duplicate) results; stores masked
        const int pos = (ki + 1) * WC + (mt * PWH + m + kj + 1);
        #pragma unroll
        for (int s = 0; s < 2; ++s) {
            const half8 af = *(const half8*)&s_winh[winh_idx(pos, s * 32 + kq8)];
            const int kkb = k * 64 + s * 32 + kq8;
            const half8 bf0 = *(const half8*)&offkt[(size_t)oc0 * KTOT + kkb];
            acc0 = __builtin_amdgcn_mfma_f32_16x16x32_f16(af, bf0, acc0, 0, 0, 0);
            if (g == 3) {
                const half8 bf1 = *(const half8*)&offkt[(size_t)(64 + m) * KTOT + kkb];
                acc1 = __builtin_amdgcn_mfma_f32_16x16x32_f16(af, bf1, acc1, 0, 0, 0);
            }
        }
    }
    #pragma unroll
    for (int r = 0; r < 4; ++r) {
        const int row = kq * 4 + r;
        if (row < PWH)
            s_off[(mt * PWH + row) * NOFF + oc0] = acc0[r];
    }
    if (g == 3 && m < 8) {
        #pragma unroll
        for (int r = 0; r < 4; ++r) {
            const int row = kq * 4 + r;
            if (row < PWH)
                s_off[(mt * PWH + row) * NOFF + 64 + m] = acc1[r];
        }
    }
    __syncthreads();

    // ---- phase A': coord/weight table, slot = (k*4+g)*32 + p ----
    for (int i = tid; i < 36 * 32; i += 512) {
        const int kg = i >> 5;                  // k*NDG + g
        const int p  = i & 31;
        float4 wv = make_float4(0.f, 0.f, 0.f, 0.f);
        unsigned c0 = 0, c1 = 0;                // pad slots: pos 0, weight 0
        if (p < PW) {
            const int k  = kg >> 2;
            const int ki = k / 3, kj = k - 3 * ki;
            const int ow = ow0 + p;
            const float offy = s_off[p * NOFF + kg * 2 + 0];
            const float offx = s_off[p * NOFF + kg * 2 + 1];
            float yv = fminf(fmaxf((float)(oh + ki) + offy, 0.0f), 57.0f);
            float xv = fminf(fmaxf((float)(ow + kj) + offx, 0.0f), 57.0f);
            const float y0f = floorf(yv), x0f = floorf(xv);
            const int y0 = (int)y0f, x0 = (int)x0f;
            const int y1 = min(y0 + 1, 57), x1 = min(x0 + 1, 57);
            const float ly = yv - y0f,       lx = xv - x0f;
            const float hy = (float)y1 - yv, hx = (float)x1 - xv;
            const bool vy0 = (unsigned)(y0 - 1) < NH;
            const bool vy1 = (unsigned)(y1 - 1) < NH;
            const bool vx0 = (unsigned)(x0 - 1) < NW;
            const bool vx1 = (unsigned)(x1 - 1) < NW;
            wv = make_float4((vy0 && vx0) ? hy * hx : 0.0f,
                             (vy0 && vx1) ? hy * lx : 0.0f,
                             (vy1 && vx0) ? ly * hx : 0.0f,
                             (vy1 && vx1) ? ly * lx : 0.0f);
            const int y0c = min(max(y0 - 1, 0), NH - 1);
            const int y1c = min(max(y1 - 1, 0), NH - 1);
            const int x0c = min(max(x0 - 1, 0), NW - 1);
            const int x1c = min(max(x1 - 1, 0), NW - 1);
            const int ry0 = y0c - oh + 2, ry1 = y1c - oh + 2;
            const int rx0 = x0c - ow0 + 2, rx1 = x1c - ow0 + 2;
            if ((unsigned)ry0 < WR && (unsigned)ry1 < WR &&
                (unsigned)rx0 < WC && (unsigned)rx1 < WC) {
                c0 = (unsigned)(ry0 * WC + rx0) | ((unsigned)(ry0 * WC + rx1) << 16);
                c1 = (unsigned)(ry1 * WC + rx0) | ((unsigned)(ry1 * WC + rx1) << 16);
            } else {                            // rare: packed clamped coords
                c0 = 0x80000000u | ((unsigned)y0c << 18) | ((unsigned)x0c << 12)
                   | ((unsigned)y1c << 6) | (unsigned)x1c;
                c1 = c0;
            }
        }
        *(float4*)&s_cww[i * 4] = wv;
        s_cwl[i * 2 + 0] = c0;
        s_cwl[i * 2 + 1] = c1;
    }
    __syncthreads();

    // ---- phase B: direct f16 A-frag build from window, zero LDS writes ----
    floatx4 accB = (floatx4){0.f, 0.f, 0.f, 0.f};
    const int tb = g * 32 + mt * PWH + m;       // table slot (+ k*128 per tap)
    float4   cw = *(const float4*)&s_cww[tb * 4];
    unsigned c0 = s_cwl[tb * 2 + 0];
    unsigned c1 = s_cwl[tb * 2 + 1];
    #pragma unroll 1
    for (int k = 0; k < NK; ++k) {
        const int tn = (k + 1 < NK ? k + 1 : k) * 128 + tb;
        const float4   cwn = *(const float4*)&s_cww[tn * 4];
        const unsigned c0n = s_cwl[tn * 2 + 0];
        const unsigned c1n = s_cwl[tn * 2 + 1];

        const _Float16* wp = &wkh[(size_t)(k * NF + g * 16 + m) * NC];
        const half8 bf0 = *(const half8*)&wp[kq8];
        const half8 bf1 = *(const half8*)&wp[32 + kq8];

        half8 q00a, q01a, q10a, q11a;           // s=0 corners (8 f16 each)
        half8 q00b, q01b, q10b, q11b;           // s=1 corners
        if (__builtin_expect((c0 & 0x80000000u) == 0, 1)) {
            const int p00 = c0 & 0xFFFF, p01 = c0 >> 16;
            const int p10 = c1 & 0xFFFF, p11 = c1 >> 16;
            const int ca = kq8, cb = 32 + kq8;
            q00a = *(const half8*)&s_winh[winh_idx(p00, ca)];
            q01a = *(const half8*)&s_winh[winh_idx(p01, ca)];
            q10a = *(const half8*)&s_winh[winh_idx(p10, ca)];
            q11a = *(const half8*)&s_winh[winh_idx(p11, ca)];
            q00b = *(const half8*)&s_winh[winh_idx(p00, cb)];
            q01b = *(const half8*)&s_winh[winh_idx(p01, cb)];
            q10b = *(const half8*)&s_winh[winh_idx(p10, cb)];
            q11b = *(const half8*)&s_winh[winh_idx(p11, cb)];
        } else {
            const int y0c = (c0 >> 18) & 63, x0c = (c0 >> 12) & 63;
            const int y1c = (c0 >> 6) & 63,  x1c = c0 & 63;
            const int i00 = (bb + y0c * NW + x0c) * NC;
            const int i01 = (bb + y0c * NW + x1c) * NC;
            const int i10 = (bb + y1c * NW + x0c) * NC;
            const int i11 = (bb + y1c * NW + x1c) * NC;
            #pragma unroll
            for (int j = 0; j < 8; ++j) {
                q00a[j] = (_Float16)x[i00 + kq8 + j];
                q01a[j] = (_Float16)x[i01 + kq8 + j];
                q10a[j] = (_Float16)x[i10 + kq8 + j];
                q11a[j] = (_Float16)x[i11 + kq8 + j];
                q00b[j] = (_Float16)x[i00 + 32 + kq8 + j];
                q01b[j] = (_Float16)x[i01 + 32 + kq8 + j];
                q10b[j] = (_Float16)x[i10 + 32 + kq8 + j];
                q11b[j] = (_Float16)x[i11 + 32 + kq8 + j];
            }
        }

        half8 af0, af1;
        #pragma unroll
        for (int j = 0; j < 8; ++j) {
            float v0 = cw.x * (float)q00a[j];       // v_fma_mix_f32 chain
            v0 = fmaf(cw.y, (float)q01a[j], v0);
            v0 = fmaf(cw.z, (float)q10a[j], v0);
            v0 = fmaf(cw.w, (float)q11a[j], v0);
            af0[j] = (_Float16)v0;
            float v1 = cw.x * (float)q00b[j];
            v1 = fmaf(cw.y, (float)q01b[j], v1);
            v1 = fmaf(cw.z, (float)q10b[j], v1);
            v1 = fmaf(cw.w, (float)q11b[j], v1);
            af1[j] = (_Float16)v1;
        }
        accB = __builtin_amdgcn_mfma_f32_16x16x32_f16(af0, bf0, accB, 0, 0, 0);
        accB = __builtin_amdgcn_mfma_f32_16x16x32_f16(af1, bf1, accB, 0, 0, 0);
        cw = cwn; c0 = c0n; c1 = c1n;
    }

    #pragma unroll
    for (int r = 0; r < 4; ++r) {
        const int row = kq * 4 + r;
        if (row < PWH)
            out[(size_t)(bb + oh * NW + ow0 + mt * PWH + row) * NF + g * 16 + m]
                = accB[r];
    }
}

extern "C" void kernel_launch(void* const* d_in, const int* in_sizes, int n_in,
                              void* d_out, int out_size, void* d_ws, size_t ws_size,
                              hipStream_t stream) {
    const float* xin  = (const float*)d_in[0];
    const float* offk = (const float*)d_in[1];
    const float* offb = (const float*)d_in[2];
    const float* wk   = (const float*)d_in[3];
    float* outp = (float*)d_out;

    _Float16* offkt = (_Float16*)((char*)d_ws + WS_OFFKT);
    _Float16* wkh   = (_Float16*)((char*)d_ws + WS_WK);

    dcn_prep<<<324, 256, 0, stream>>>(offk, wk, offkt, wkh);
    dcn_main<<<NBLK, 512, 0, stream>>>(xin, offkt, offb, wkh, outp);
}